// Round 1
// baseline (894.446 us; speedup 1.0000x reference)
//
#include <hip/hip_runtime.h>

#define N_NODES 50000
#define N_RELSR 20
#define R_TOT   41          // 2*N_RELSR + 1
#define N_EDGES 500000
#define EMB     16
#define NCLS    16
#define NB      40
#define E_TOT   (2 * N_EDGES + N_NODES)   // 1,050,000
#define NE_COL  (N_NODES * EMB)           // 800,000

// decode enriched edge i -> (s, o, r)
__device__ __forceinline__ void edge_decode(int i, const int* __restrict__ src,
                                            const int* __restrict__ dst,
                                            const int* __restrict__ rel,
                                            int& s, int& o, int& r) {
    if (i < N_EDGES) {
        s = src[i]; o = dst[i]; r = rel[i];
    } else if (i < 2 * N_EDGES) {
        int j = i - N_EDGES;
        s = dst[j]; o = src[j]; r = rel[j] + N_RELSR;
    } else {
        int n = i - 2 * N_EDGES;
        s = n; o = n; r = 2 * N_RELSR;
    }
}

// ---- K1: segment counts -----------------------------------------------------
__global__ void k_count(const int* __restrict__ src, const int* __restrict__ dst,
                        const int* __restrict__ rel, int* __restrict__ cnt) {
    int i = blockIdx.x * blockDim.x + threadIdx.x;
    if (i >= E_TOT) return;
    int s, o, r;
    edge_decode(i, src, dst, rel, s, o, r);
    atomicAdd(&cnt[r * N_NODES + s], 1);
}

// ---- K1b: per-edge normalization v = 1/cnt[seg] -----------------------------
__global__ void k_inv(const int* __restrict__ src, const int* __restrict__ dst,
                      const int* __restrict__ rel, const int* __restrict__ cnt,
                      float* __restrict__ v) {
    int i = blockIdx.x * blockDim.x + threadIdx.x;
    if (i >= E_TOT) return;
    int s, o, r;
    edge_decode(i, src, dst, rel, s, o, r);
    v[i] = 1.0f / (float)cnt[r * N_NODES + s];
}

// ---- K2: w1[r,n,e] = sum_b comps1[r,b] * bases1[b,n,e] ----------------------
// one thread per flattened column j = n*EMB+e; 40 bases values in registers
__global__ void k_w1(const float* __restrict__ comps1, const float* __restrict__ bases1,
                     float* __restrict__ w1) {
    __shared__ float c1[R_TOT * NB];
    for (int t = threadIdx.x; t < R_TOT * NB; t += blockDim.x) c1[t] = comps1[t];
    __syncthreads();
    int j = blockIdx.x * blockDim.x + threadIdx.x;
    if (j >= NE_COL) return;
    float base[NB];
#pragma unroll
    for (int b = 0; b < NB; b++) base[b] = bases1[(size_t)b * NE_COL + j];
    for (int r = 0; r < R_TOT; r++) {
        float acc = 0.f;
#pragma unroll
        for (int b = 0; b < NB; b++) acc += c1[r * NB + b] * base[b];
        w1[(size_t)r * NE_COL + j] = acc;
    }
}

// ---- K3: w2[r,e,c] = sum_b comps2[r,b] * bases2[b,e,c] ----------------------
__global__ void k_w2(const float* __restrict__ comps2, const float* __restrict__ bases2,
                     float* __restrict__ w2) {
    int r = blockIdx.x;        // 41 blocks
    int t = threadIdx.x;       // 256 = EMB*NCLS
    float acc = 0.f;
#pragma unroll 8
    for (int b = 0; b < NB; b++) acc += comps2[r * NB + b] * bases2[b * (EMB * NCLS) + t];
    w2[r * (EMB * NCLS) + t] = acc;
}

// ---- K4: layer-1 edge scatter: h[s,e] += v * w1[r,o,e] ----------------------
// grid exact: E_TOT*16 threads, 16 lanes per edge
__global__ void k_l1(const int* __restrict__ src, const int* __restrict__ dst,
                     const int* __restrict__ rel, const float* __restrict__ v,
                     const float* __restrict__ w1, float* __restrict__ h) {
    int t = blockIdx.x * blockDim.x + threadIdx.x;
    int i = t >> 4, e = t & 15;
    int s, o, r;
    edge_decode(i, src, dst, rel, s, o, r);
    float val = v[i] * w1[(size_t)r * NE_COL + o * EMB + e];
    atomicAdd(&h[s * EMB + e], val);
}

// ---- K4-alt (fallback, no w1 buffer): on-the-fly basis contraction ----------
__global__ void k_l1_fly(const int* __restrict__ src, const int* __restrict__ dst,
                         const int* __restrict__ rel, const float* __restrict__ v,
                         const float* __restrict__ comps1, const float* __restrict__ bases1,
                         float* __restrict__ h) {
    __shared__ float c1[R_TOT * NB];
    for (int t = threadIdx.x; t < R_TOT * NB; t += blockDim.x) c1[t] = comps1[t];
    __syncthreads();
    int t = blockIdx.x * blockDim.x + threadIdx.x;
    int i = t >> 4, e = t & 15;
    int s, o, r;
    edge_decode(i, src, dst, rel, s, o, r);
    const float* cr = &c1[r * NB];
    float acc = 0.f;
#pragma unroll 8
    for (int b = 0; b < NB; b++) acc += cr[b] * bases1[(size_t)b * NE_COL + o * EMB + e];
    atomicAdd(&h[s * EMB + e], v[i] * acc);
}

// ---- K5: h = relu(h + bias1) ------------------------------------------------
__global__ void k_bias_relu(float* __restrict__ h, const float* __restrict__ bias1) {
    int j = blockIdx.x * blockDim.x + threadIdx.x;
    if (j >= NE_COL) return;
    h[j] = fmaxf(h[j] + bias1[j & 15], 0.f);
}

// ---- K6: out init = bias2 ---------------------------------------------------
__global__ void k_out_init(float* __restrict__ out, const float* __restrict__ bias2) {
    int j = blockIdx.x * blockDim.x + threadIdx.x;
    if (j >= N_NODES * NCLS) return;
    out[j] = bias2[j & 15];
}

// ---- K7: layer-2 fused edge pass: out[s,c] += v * sum_e h[o,e]*w2[r,e,c] ----
// w2 staged in LDS with padded r-stride (256 -> 260) to break bank aliasing.
#define W2_STRIDE 260
__global__ void k_l2(const int* __restrict__ src, const int* __restrict__ dst,
                     const int* __restrict__ rel, const float* __restrict__ v,
                     const float* __restrict__ h, const float* __restrict__ w2,
                     float* __restrict__ out) {
    __shared__ float w2s[R_TOT * W2_STRIDE];
    for (int t = threadIdx.x; t < R_TOT * (EMB * NCLS); t += blockDim.x) {
        int r = t >> 8;          // /256
        int x = t & 255;
        w2s[r * W2_STRIDE + x] = w2[t];
    }
    __syncthreads();
    int t = blockIdx.x * blockDim.x + threadIdx.x;
    int i = t >> 4, c = t & 15;
    int s, o, r;
    edge_decode(i, src, dst, rel, s, o, r);
    float hv = h[o * EMB + c];           // lane c holds h[o,c]
    const float* wr = &w2s[r * W2_STRIDE];
    float acc = 0.f;
#pragma unroll
    for (int e = 0; e < 16; e++) {
        float he = __shfl(hv, e, 16);    // h[o,e] from lane e of this edge's 16-group
        acc += he * wr[e * NCLS + c];
    }
    atomicAdd(&out[s * NCLS + c], v[i] * acc);
}

extern "C" void kernel_launch(void* const* d_in, const int* in_sizes, int n_in,
                              void* d_out, int out_size, void* d_ws, size_t ws_size,
                              hipStream_t stream) {
    const int*   src    = (const int*)d_in[0];
    const int*   dst    = (const int*)d_in[1];
    const int*   rel    = (const int*)d_in[2];
    const float* comps1 = (const float*)d_in[3];
    const float* bases1 = (const float*)d_in[4];
    const float* comps2 = (const float*)d_in[5];
    const float* bases2 = (const float*)d_in[6];
    const float* bias1  = (const float*)d_in[7];
    const float* bias2  = (const float*)d_in[8];
    float* out = (float*)d_out;

    char* ws = (char*)d_ws;
    size_t off = 0;
    int*   cnt = (int*)(ws + off);   off += (size_t)R_TOT * N_NODES * 4;     // 8,200,000
    float* h   = (float*)(ws + off); off += (size_t)NE_COL * 4;              // 3,200,000
    float* v   = (float*)(ws + off); off += (size_t)E_TOT * 4;               // 4,200,000
    float* w2  = (float*)(ws + off); off += (size_t)R_TOT * EMB * NCLS * 4;  // 41,984
    size_t off_small = off;
    float* w1  = (float*)(ws + off); off += (size_t)R_TOT * NE_COL * 4;      // 131,200,000
    const bool materialize_w1 = (ws_size >= off);
    (void)off_small; (void)in_sizes; (void)n_in; (void)out_size;

    // zero cnt + h (adjacent at ws start); everything else is fully overwritten
    hipMemsetAsync(d_ws, 0, (size_t)(R_TOT * N_NODES + NE_COL) * 4, stream);

    const int BLK = 256;
    const int g_edge  = (E_TOT + BLK - 1) / BLK;      // 4102
    const int g_col   = (NE_COL + BLK - 1) / BLK;     // 3125
    const int g_lane  = (E_TOT * 16) / BLK;           // 65,625 (exact)

    k_count<<<g_edge, BLK, 0, stream>>>(src, dst, rel, cnt);
    k_inv<<<g_edge, BLK, 0, stream>>>(src, dst, rel, cnt, v);
    k_w2<<<R_TOT, EMB * NCLS, 0, stream>>>(comps2, bases2, w2);

    if (materialize_w1) {
        k_w1<<<g_col, BLK, 0, stream>>>(comps1, bases1, w1);
        k_l1<<<g_lane, BLK, 0, stream>>>(src, dst, rel, v, w1, h);
    } else {
        k_l1_fly<<<g_lane, BLK, 0, stream>>>(src, dst, rel, v, comps1, bases1, h);
    }

    k_bias_relu<<<g_col, BLK, 0, stream>>>(h, bias1);
    k_out_init<<<g_col, BLK, 0, stream>>>(out, bias2);
    k_l2<<<g_lane, BLK, 0, stream>>>(src, dst, rel, v, h, w2, out);
}

// Round 2
// 648.742 us; speedup vs baseline: 1.3787x; 1.3787x over previous
//
#include <hip/hip_runtime.h>

#define N_NODES 50000
#define N_RELSR 20
#define R_TOT   41          // 2*N_RELSR + 1
#define N_EDGES 500000
#define EMB     16
#define NCLS    16
#define NB      40
#define E_TOT   (2 * N_EDGES + N_NODES)   // 1,050,000
#define NE_COL  (N_NODES * EMB)           // 800,000

// decode enriched edge i -> (s, o, r)
__device__ __forceinline__ void edge_decode(int i, const int* __restrict__ src,
                                            const int* __restrict__ dst,
                                            const int* __restrict__ rel,
                                            int& s, int& o, int& r) {
    if (i < N_EDGES) {
        s = src[i]; o = dst[i]; r = rel[i];
    } else if (i < 2 * N_EDGES) {
        int j = i - N_EDGES;
        s = dst[j]; o = src[j]; r = rel[j] + N_RELSR;
    } else {
        int n = i - 2 * N_EDGES;
        s = n; o = n; r = 2 * N_RELSR;
    }
}

// ---- K1: segment counts + per-node degree ----------------------------------
__global__ void k_count(const int* __restrict__ src, const int* __restrict__ dst,
                        const int* __restrict__ rel, int* __restrict__ cnt,
                        int* __restrict__ deg) {
    int i = blockIdx.x * blockDim.x + threadIdx.x;
    if (i >= E_TOT) return;
    int s, o, r;
    edge_decode(i, src, dst, rel, s, o, r);
    atomicAdd(&cnt[r * N_NODES + s], 1);
    atomicAdd(&deg[s], 1);
}

// ---- K2: exclusive scan of deg -> off[N+1], cursor[N] (single block) --------
#define SCAN_T 1024
__global__ void k_scan(const int* __restrict__ deg, int* __restrict__ off,
                       int* __restrict__ cursor) {
    __shared__ int sums[SCAN_T];
    int t = threadIdx.x;
    const int CH = (N_NODES + SCAN_T - 1) / SCAN_T;   // 49
    int beg = t * CH;
    int end = min(beg + CH, N_NODES);
    int sum = 0;
    for (int i = beg; i < end; i++) sum += deg[i];
    sums[t] = sum;
    __syncthreads();
    // inclusive Hillis-Steele scan over 1024 partial sums
    for (int d = 1; d < SCAN_T; d <<= 1) {
        int val = (t >= d) ? sums[t - d] : 0;
        __syncthreads();
        sums[t] += val;
        __syncthreads();
    }
    int run = (t == 0) ? 0 : sums[t - 1];             // exclusive prefix
    for (int i = beg; i < end; i++) {
        off[i] = run; cursor[i] = run;
        run += deg[i];
    }
    if (t == SCAN_T - 1) off[N_NODES] = run;          // == E_TOT
}

// ---- K3: fill CSR records {(r<<16)|o, v} sorted by s ------------------------
__global__ void k_fill(const int* __restrict__ src, const int* __restrict__ dst,
                       const int* __restrict__ rel, const int* __restrict__ cnt,
                       int* __restrict__ cursor, int2* __restrict__ recs) {
    int i = blockIdx.x * blockDim.x + threadIdx.x;
    if (i >= E_TOT) return;
    int s, o, r;
    edge_decode(i, src, dst, rel, s, o, r);
    float v = 1.0f / (float)cnt[r * N_NODES + s];
    int pos = atomicAdd(&cursor[s], 1);
    recs[pos] = make_int2((r << 16) | o, __float_as_int(v));
}

// ---- K4: w1[r,n,e] = sum_b comps1[r,b] * bases1[b,n,e] ----------------------
__global__ void k_w1(const float* __restrict__ comps1, const float* __restrict__ bases1,
                     float* __restrict__ w1) {
    __shared__ float c1[R_TOT * NB];
    for (int t = threadIdx.x; t < R_TOT * NB; t += blockDim.x) c1[t] = comps1[t];
    __syncthreads();
    int j = blockIdx.x * blockDim.x + threadIdx.x;
    if (j >= NE_COL) return;
    float base[NB];
#pragma unroll
    for (int b = 0; b < NB; b++) base[b] = bases1[(size_t)b * NE_COL + j];
    for (int r = 0; r < R_TOT; r++) {
        float acc = 0.f;
#pragma unroll
        for (int b = 0; b < NB; b++) acc += c1[r * NB + b] * base[b];
        w1[(size_t)r * NE_COL + j] = acc;
    }
}

// ---- K5: w2[r,e,c] = sum_b comps2[r,b] * bases2[b,e,c] ----------------------
__global__ void k_w2(const float* __restrict__ comps2, const float* __restrict__ bases2,
                     float* __restrict__ w2) {
    int r = blockIdx.x;        // 41 blocks
    int t = threadIdx.x;       // 256 = EMB*NCLS
    float acc = 0.f;
#pragma unroll 8
    for (int b = 0; b < NB; b++) acc += comps2[r * NB + b] * bases2[b * (EMB * NCLS) + t];
    w2[r * (EMB * NCLS) + t] = acc;
}

// ---- K6: layer-1 gather: h[s,e] = relu(bias1[e] + sum_j v*w1[r,o,e]) --------
__global__ void k_l1_gather(const int* __restrict__ off, const int2* __restrict__ recs,
                            const float* __restrict__ w1, const float* __restrict__ bias1,
                            float* __restrict__ h) {
    int t = blockIdx.x * blockDim.x + threadIdx.x;     // N_NODES*16 exact
    int s = t >> 4, e = t & 15;
    int beg = off[s], end = off[s + 1];
    float acc = 0.f;
    for (int j = beg; j < end; j++) {
        int2 rec = recs[j];
        int o = rec.x & 0xFFFF, r = rec.x >> 16;
        float v = __int_as_float(rec.y);
        acc += v * w1[(size_t)r * NE_COL + o * EMB + e];
    }
    h[t] = fmaxf(acc + bias1[e], 0.f);
}

// ---- K6-alt (fallback if ws too small for w1): on-the-fly basis contraction -
__global__ void k_l1_gather_fly(const int* __restrict__ off, const int2* __restrict__ recs,
                                const float* __restrict__ comps1,
                                const float* __restrict__ bases1,
                                const float* __restrict__ bias1, float* __restrict__ h) {
    __shared__ float c1[R_TOT * NB];
    for (int q = threadIdx.x; q < R_TOT * NB; q += blockDim.x) c1[q] = comps1[q];
    __syncthreads();
    int t = blockIdx.x * blockDim.x + threadIdx.x;
    int s = t >> 4, e = t & 15;
    int beg = off[s], end = off[s + 1];
    float acc = 0.f;
    for (int j = beg; j < end; j++) {
        int2 rec = recs[j];
        int o = rec.x & 0xFFFF, r = rec.x >> 16;
        float v = __int_as_float(rec.y);
        const float* cr = &c1[r * NB];
        float w = 0.f;
#pragma unroll 8
        for (int b = 0; b < NB; b++) w += cr[b] * bases1[(size_t)b * NE_COL + o * EMB + e];
        acc += v * w;
    }
    h[t] = fmaxf(acc + bias1[e], 0.f);
}

// ---- K7: layer-2 gather: out[s,c] = bias2[c] + sum_j v * (h[o,:]·w2[r,:,c]) -
#define W2_STRIDE 260
__global__ void k_l2_gather(const int* __restrict__ off, const int2* __restrict__ recs,
                            const float* __restrict__ h, const float* __restrict__ w2,
                            const float* __restrict__ bias2, float* __restrict__ out) {
    __shared__ float w2s[R_TOT * W2_STRIDE];
    for (int q = threadIdx.x; q < R_TOT * (EMB * NCLS); q += blockDim.x) {
        int r = q >> 8;
        int x = q & 255;
        w2s[r * W2_STRIDE + x] = w2[q];
    }
    __syncthreads();
    int t = blockIdx.x * blockDim.x + threadIdx.x;     // N_NODES*16 exact
    int s = t >> 4, c = t & 15;
    int beg = off[s], end = off[s + 1];
    float acc = 0.f;
    for (int j = beg; j < end; j++) {
        int2 rec = recs[j];
        int o = rec.x & 0xFFFF, r = rec.x >> 16;
        float v = __int_as_float(rec.y);
        float hc = h[o * EMB + c];                     // lane c holds h[o,c]
        const float* wr = &w2s[r * W2_STRIDE];
        float a2 = 0.f;
#pragma unroll
        for (int e = 0; e < 16; e++) {
            a2 += __shfl(hc, e, 16) * wr[e * NCLS + c];
        }
        acc += v * a2;
    }
    out[s * NCLS + c] = acc + bias2[c];
}

extern "C" void kernel_launch(void* const* d_in, const int* in_sizes, int n_in,
                              void* d_out, int out_size, void* d_ws, size_t ws_size,
                              hipStream_t stream) {
    const int*   src    = (const int*)d_in[0];
    const int*   dst    = (const int*)d_in[1];
    const int*   rel    = (const int*)d_in[2];
    const float* comps1 = (const float*)d_in[3];
    const float* bases1 = (const float*)d_in[4];
    const float* comps2 = (const float*)d_in[5];
    const float* bases2 = (const float*)d_in[6];
    const float* bias1  = (const float*)d_in[7];
    const float* bias2  = (const float*)d_in[8];
    float* out = (float*)d_out;
    (void)in_sizes; (void)n_in; (void)out_size;

    char* ws = (char*)d_ws;
    size_t off_b = 0;
    // w1 region first; cnt aliases its head (cnt dead before k_w1 writes w1)
    float* w1     = (float*)(ws + off_b);
    int*   cnt    = (int*)(ws + off_b);   off_b += (size_t)R_TOT * NE_COL * 4;   // 131,200,000
    size_t w1_end = off_b;
    int*   deg    = (int*)(ws + off_b);   off_b += (size_t)N_NODES * 4;
    int*   off    = (int*)(ws + off_b);   off_b += (size_t)(N_NODES + 1) * 4;
    int*   cursor = (int*)(ws + off_b);   off_b += (size_t)N_NODES * 4;
    int2*  recs   = (int2*)(ws + off_b);  off_b += (size_t)E_TOT * 8;
    float* h      = (float*)(ws + off_b); off_b += (size_t)NE_COL * 4;
    float* w2     = (float*)(ws + off_b); off_b += (size_t)R_TOT * EMB * NCLS * 4;
    const bool materialize_w1 = (ws_size >= off_b);
    if (!materialize_w1) {
        // compact layout without w1: cnt gets its own region
        off_b = 0;
        cnt    = (int*)(ws + off_b);   off_b += (size_t)R_TOT * N_NODES * 4;
        deg    = (int*)(ws + off_b);   off_b += (size_t)N_NODES * 4;
        off    = (int*)(ws + off_b);   off_b += (size_t)(N_NODES + 1) * 4;
        cursor = (int*)(ws + off_b);   off_b += (size_t)N_NODES * 4;
        recs   = (int2*)(ws + off_b);  off_b += (size_t)E_TOT * 8;
        h      = (float*)(ws + off_b); off_b += (size_t)NE_COL * 4;
        w2     = (float*)(ws + off_b); off_b += (size_t)R_TOT * EMB * NCLS * 4;
    }
    (void)w1_end;

    // zero cnt and deg
    hipMemsetAsync(cnt, 0, (size_t)R_TOT * N_NODES * 4, stream);
    hipMemsetAsync(deg, 0, (size_t)N_NODES * 4, stream);

    const int BLK = 256;
    const int g_edge = (E_TOT + BLK - 1) / BLK;       // 4102
    const int g_col  = (NE_COL + BLK - 1) / BLK;      // 3125
    const int g_node = (N_NODES * 16) / BLK;          // 3125 (exact)

    k_count<<<g_edge, BLK, 0, stream>>>(src, dst, rel, cnt, deg);
    k_scan<<<1, SCAN_T, 0, stream>>>(deg, off, cursor);
    k_fill<<<g_edge, BLK, 0, stream>>>(src, dst, rel, cnt, cursor, recs);
    k_w2<<<R_TOT, EMB * NCLS, 0, stream>>>(comps2, bases2, w2);

    if (materialize_w1) {
        k_w1<<<g_col, BLK, 0, stream>>>(comps1, bases1, w1);   // overwrites cnt (dead)
        k_l1_gather<<<g_node, BLK, 0, stream>>>(off, recs, w1, bias1, h);
    } else {
        k_l1_gather_fly<<<g_node, BLK, 0, stream>>>(off, recs, comps1, bases1, bias1, h);
    }

    k_l2_gather<<<g_node, BLK, 0, stream>>>(off, recs, h, w2, bias2, out);
}